// Round 1
// baseline (628.436 us; speedup 1.0000x reference)
//
#include <hip/hip_runtime.h>

#define NN 8192
#define EE 131072
#define HH 128
#define NEGV -1.0e30f

// ---------------- GCN helpers ----------------

__global__ __launch_bounds__(256) void k_deg(const int* __restrict__ dst, float* __restrict__ deg) {
    int t = blockIdx.x * 256 + threadIdx.x;
    if (t < EE) atomicAdd(&deg[dst[t]], 1.0f);
}

__global__ __launch_bounds__(256) void k_rsq(const float* __restrict__ deg, float* __restrict__ degf,
                                             float* __restrict__ rsq) {
    int t = blockIdx.x * 256 + threadIdx.x;
    if (t < NN) {
        float d = deg[t] + 1.0f;   // +1 self loop
        degf[t] = d;
        rsq[t] = (float)(1.0 / sqrt((double)d));
    }
}

__global__ __launch_bounds__(256) void k_xw1(const float* __restrict__ x, const float* __restrict__ w,
                                             float* __restrict__ out) {
    int t = blockIdx.x * 256 + threadIdx.x;   // N*H threads
    int i = t >> 7, j = t & 127;
    out[t] = x[i * 2] * w[j * 2] + x[i * 2 + 1] * w[j * 2 + 1];
}

__global__ __launch_bounds__(256) void k_scatter(const int* __restrict__ src, const int* __restrict__ dst,
                                                 const float* __restrict__ rsq, const float* __restrict__ xw,
                                                 float* __restrict__ agg) {
    int t = blockIdx.x * 256 + threadIdx.x;   // E*H threads
    int e = t >> 7, j = t & 127;
    int s = src[e], d = dst[e];
    atomicAdd(&agg[d * HH + j], rsq[s] * rsq[d] * xw[s * HH + j]);
}

__global__ __launch_bounds__(256) void k_bias_act(const float* __restrict__ agg, const float* __restrict__ xw,
                                                  const float* __restrict__ degf, const float* __restrict__ b,
                                                  float* __restrict__ out) {
    int t = blockIdx.x * 256 + threadIdx.x;   // N*H
    int i = t >> 7, j = t & 127;
    float v = agg[t] + xw[t] / degf[i] + b[j];
    out[t] = fmaxf(v, 0.0f);
}

// ---------------- weight prep: transposes + folded-z biases ----------------
// T holds 7 transposed 128x128 mats: 0 conv2, 1 np1(h-part), 2 np2, 3 src, 4 tgt, 5 inv1(h_u), 6 inv1(h_v)

__global__ __launch_bounds__(256) void k_prep(const float* __restrict__ conv2_w, const float* __restrict__ np1_w,
                                              const float* __restrict__ np2_w, const float* __restrict__ src_w,
                                              const float* __restrict__ tgt_w, const float* __restrict__ inv1_w,
                                              const float* __restrict__ np1_b, const float* __restrict__ inv1_b,
                                              const float* __restrict__ z, float* __restrict__ T,
                                              float* __restrict__ c1, float* __restrict__ cz) {
    int y = blockIdx.y;
    if (y < 7) {
        int t = blockIdx.x * 256 + threadIdx.x;   // 16384 per matrix
        int j = t >> 7, k = t & 127;
        const float* W; int stride, off;
        switch (y) {
            case 0:  W = conv2_w; stride = 128; off = 0;   break;
            case 1:  W = np1_w;   stride = 256; off = 0;   break;
            case 2:  W = np2_w;   stride = 128; off = 0;   break;
            case 3:  W = src_w;   stride = 128; off = 0;   break;
            case 4:  W = tgt_w;   stride = 128; off = 0;   break;
            case 5:  W = inv1_w;  stride = 384; off = 0;   break;
            default: W = inv1_w;  stride = 384; off = 128; break;
        }
        T[y * 16384 + k * 128 + j] = W[j * stride + off + k];
    } else if (blockIdx.x == 0) {
        int tid = threadIdx.x;
        if (tid < 128) {
            float s = np1_b[tid];
            for (int k = 0; k < 128; k++) s += z[k] * np1_w[tid * 256 + 128 + k];
            c1[tid] = s;
        } else {
            int j = tid - 128;
            float s = inv1_b[j];
            for (int k = 0; k < 128; k++) s += z[k] * inv1_w[j * 384 + 256 + k];
            cz[j] = s;
        }
    }
}

// ---------------- generic [8192x128] @ WT[128x128] (+bias)(+relu) ----------------

__global__ __launch_bounds__(256) void k_gemm128(const float* __restrict__ A, const float* __restrict__ WT,
                                                 const float* __restrict__ bias, float* __restrict__ out,
                                                 int relu) {
    __shared__ float As[32][33];
    __shared__ float Bs[32][128];
    int tid = threadIdx.x;
    int tx = tid & 31, ty = tid >> 5;
    int row0 = blockIdx.x * 32;
    float acc[4][4] = {};
    for (int k0 = 0; k0 < 128; k0 += 32) {
        {
            int r = tid >> 3, k = (tid & 7) << 2;
            float4 v = *(const float4*)&A[(row0 + r) * HH + k0 + k];
            As[r][k] = v.x; As[r][k + 1] = v.y; As[r][k + 2] = v.z; As[r][k + 3] = v.w;
        }
#pragma unroll
        for (int i = 0; i < 4; i++) {
            int kk = (tid >> 5) + i * 8;
            int c = (tid & 31) << 2;
            *(float4*)&Bs[kk][c] = *(const float4*)&WT[(k0 + kk) * HH + c];
        }
        __syncthreads();
#pragma unroll 8
        for (int kk = 0; kk < 32; kk++) {
            float a0 = As[ty * 4 + 0][kk], a1 = As[ty * 4 + 1][kk];
            float a2 = As[ty * 4 + 2][kk], a3 = As[ty * 4 + 3][kk];
            float4 b = *(const float4*)&Bs[kk][tx * 4];
            acc[0][0] = fmaf(a0, b.x, acc[0][0]); acc[0][1] = fmaf(a0, b.y, acc[0][1]);
            acc[0][2] = fmaf(a0, b.z, acc[0][2]); acc[0][3] = fmaf(a0, b.w, acc[0][3]);
            acc[1][0] = fmaf(a1, b.x, acc[1][0]); acc[1][1] = fmaf(a1, b.y, acc[1][1]);
            acc[1][2] = fmaf(a1, b.z, acc[1][2]); acc[1][3] = fmaf(a1, b.w, acc[1][3]);
            acc[2][0] = fmaf(a2, b.x, acc[2][0]); acc[2][1] = fmaf(a2, b.y, acc[2][1]);
            acc[2][2] = fmaf(a2, b.z, acc[2][2]); acc[2][3] = fmaf(a2, b.w, acc[2][3]);
            acc[3][0] = fmaf(a3, b.x, acc[3][0]); acc[3][1] = fmaf(a3, b.y, acc[3][1]);
            acc[3][2] = fmaf(a3, b.z, acc[3][2]); acc[3][3] = fmaf(a3, b.w, acc[3][3]);
        }
        __syncthreads();
    }
#pragma unroll
    for (int i = 0; i < 4; i++) {
        float4 v = make_float4(acc[i][0], acc[i][1], acc[i][2], acc[i][3]);
        if (bias) {
            v.x += bias[tx * 4]; v.y += bias[tx * 4 + 1];
            v.z += bias[tx * 4 + 2]; v.w += bias[tx * 4 + 3];
        }
        if (relu) {
            v.x = fmaxf(v.x, 0.f); v.y = fmaxf(v.y, 0.f);
            v.z = fmaxf(v.z, 0.f); v.w = fmaxf(v.w, 0.f);
        }
        *(float4*)&out[(row0 + ty * 4 + i) * HH + tx * 4] = v;
    }
}

// ---------------- candidate counts + valid flags ----------------

__global__ __launch_bounds__(256) void k_cnt_valid(const int* __restrict__ depth, const float* __restrict__ x,
                                                   int* __restrict__ cnt, float* __restrict__ out) {
    int v = blockIdx.x * 256 + threadIdx.x;
    if (v >= NN) return;
    int limit = depth[v] + 1;   // depth[v]-1+DEPTH_PERTURB
    int lo = 0, hi = NN;
    while (lo < hi) { int mid = (lo + hi) >> 1; if (depth[mid] <= limit) lo = mid + 1; else hi = mid; }
    cnt[v] = lo;
    int type = (int)(x[v * 2] + 0.5f);
    bool tv = (depth[v] >= 1) && (type != 0);
    out[4 * NN * 2 + v * 2 + 0] = (tv && lo >= 1) ? 1.0f : 0.0f;
    out[4 * NN * 2 + v * 2 + 1] = (tv && type == 2 && lo >= 2) ? 1.0f : 0.0f;
}

// ---------------- fused masked GEMM + top-2 (stage 1: per u-segment partials) ----------------

__global__ __launch_bounds__(256) void k_top2_stage1(const float* __restrict__ Ht, const float* __restrict__ Hs,
                                                     const int* __restrict__ cnt,
                                                     float* __restrict__ pval, int* __restrict__ pidx) {
    __shared__ float HtS[64][132];
    __shared__ float HsS[64][132];
    __shared__ int cntS[64];
    int tid = threadIdx.x;
    int v0 = blockIdx.x * 64;
    int seg = blockIdx.y;
    int useg0 = seg * 1024;
    if (tid < 64) cntS[tid] = cnt[v0 + tid];
    __syncthreads();
    int cmax = cntS[63];   // depth sorted -> cnt nondecreasing
    if (useg0 >= cmax) {   // whole segment masked for every row in block
        if (tid < 64) {
            int o = ((v0 + tid) * 8 + seg) * 2;
            pval[o] = NEGV;     pidx[o] = useg0;
            pval[o + 1] = NEGV; pidx[o + 1] = useg0 + 1;
        }
        return;
    }
    for (int t = tid; t < 64 * 32; t += 256) {
        int r = t >> 5; int k = (t & 31) << 2;
        *(float4*)&HtS[r][k] = *(const float4*)&Ht[(v0 + r) * HH + k];
    }
    int tx = tid & 15, ty = tid >> 4;
    float t1v[4], t2v[4]; int t1i[4], t2i[4];
#pragma unroll
    for (int i = 0; i < 4; i++) { t1v[i] = NEGV; t2v[i] = NEGV; t1i[i] = 0x7fffffff; t2i[i] = 0x7fffffff; }
    int uend = useg0 + 1024; if (uend > cmax) uend = cmax;
    for (int ub = useg0; ub < uend; ub += 64) {
        __syncthreads();
        for (int t = tid; t < 64 * 32; t += 256) {
            int r = t >> 5; int k = (t & 31) << 2;
            *(float4*)&HsS[r][k] = *(const float4*)&Hs[(ub + r) * HH + k];
        }
        __syncthreads();
        float acc[4][4] = {};
#pragma unroll 8
        for (int k = 0; k < 128; k += 4) {
            float4 a[4], b[4];
#pragma unroll
            for (int i = 0; i < 4; i++) a[i] = *(const float4*)&HtS[ty + 16 * i][k];
#pragma unroll
            for (int j = 0; j < 4; j++) b[j] = *(const float4*)&HsS[tx + 16 * j][k];
#pragma unroll
            for (int i = 0; i < 4; i++)
#pragma unroll
                for (int j = 0; j < 4; j++) {
                    acc[i][j] = fmaf(a[i].x, b[j].x, acc[i][j]);
                    acc[i][j] = fmaf(a[i].y, b[j].y, acc[i][j]);
                    acc[i][j] = fmaf(a[i].z, b[j].z, acc[i][j]);
                    acc[i][j] = fmaf(a[i].w, b[j].w, acc[i][j]);
                }
        }
#pragma unroll
        for (int j = 0; j < 4; j++) {
            int u = ub + tx + 16 * j;
#pragma unroll
            for (int i = 0; i < 4; i++) {
                int c = cntS[ty + 16 * i];
                float val = (u < c) ? acc[i][j] : NEGV;   // masked: NEG with real index (top_k tie semantics)
                if (val > t1v[i] || (val == t1v[i] && u < t1i[i])) {
                    t2v[i] = t1v[i]; t2i[i] = t1i[i]; t1v[i] = val; t1i[i] = u;
                } else if (val > t2v[i] || (val == t2v[i] && u < t2i[i])) {
                    t2v[i] = val; t2i[i] = u;
                }
            }
        }
    }
    __syncthreads();
    // cross-thread merge: reuse LDS tiles as (val,idx) buffers
    float* mv = &HsS[0][0];
    int* mi = (int*)&HtS[0][0];
#pragma unroll
    for (int i = 0; i < 4; i++) {
        int row = ty + 16 * i;
        mv[row * 32 + tx * 2 + 0] = t1v[i]; mi[row * 32 + tx * 2 + 0] = t1i[i];
        mv[row * 32 + tx * 2 + 1] = t2v[i]; mi[row * 32 + tx * 2 + 1] = t2i[i];
    }
    __syncthreads();
    if (tid < 64) {
        float v1 = NEGV, v2 = NEGV; int i1 = 0x7fffffff, i2 = 0x7fffffff;
        for (int q = 0; q < 32; q++) {
            float val = mv[tid * 32 + q]; int idx = mi[tid * 32 + q];
            if (val > v1 || (val == v1 && idx < i1)) { v2 = v1; i2 = i1; v1 = val; i1 = idx; }
            else if (val > v2 || (val == v2 && idx < i2)) { v2 = val; i2 = idx; }
        }
        int o = ((v0 + tid) * 8 + seg) * 2;
        pval[o] = v1;     pidx[o] = i1;
        pval[o + 1] = v2; pidx[o + 1] = i2;
    }
}

// ---------------- stage 2: merge segment partials, emit top_vals/top_idx ----------------

__global__ __launch_bounds__(256) void k_top2_merge(const float* __restrict__ pval, const int* __restrict__ pidx,
                                                    float* __restrict__ out, int* __restrict__ tidx) {
    int v = blockIdx.x * 256 + threadIdx.x;
    if (v >= NN) return;
    float v1 = NEGV, v2 = NEGV; int i1 = 0x7fffffff, i2 = 0x7fffffff;
    for (int t = 0; t < 16; t++) {
        float val = pval[v * 16 + t]; int idx = pidx[v * 16 + t];
        if (val > v1 || (val == v1 && idx < i1)) { v2 = v1; i2 = i1; v1 = val; i1 = idx; }
        else if (val > v2 || (val == v2 && idx < i2)) { v2 = val; i2 = idx; }
    }
    out[v * 2 + 0] = v1; out[v * 2 + 1] = v2;                    // top_vals
    out[2 * NN * 2 + v * 2 + 0] = (float)i1;                     // top_idx
    out[2 * NN * 2 + v * 2 + 1] = (float)i2;
    tidx[v * 2] = i1; tidx[v * 2 + 1] = i2;
}

// ---------------- inversion-bit epilogue: logit = inv2 . relu(P[u]+Q[v]+cz) + b ----------------

__global__ __launch_bounds__(256) void k_inv(const float* __restrict__ P, const float* __restrict__ Q,
                                             const float* __restrict__ cz, const float* __restrict__ w2,
                                             const float* __restrict__ b2, const int* __restrict__ tidx,
                                             float* __restrict__ out) {
    int gid = blockIdx.x * 256 + threadIdx.x;
    int wid = gid >> 6;
    int lane = gid & 63;
    if (wid >= NN * 2) return;
    int v = wid >> 1;
    int u = tidx[wid]; if (u > NN - 1) u = NN - 1; if (u < 0) u = 0;
    float h0 = fmaxf(P[u * HH + lane] + Q[v * HH + lane] + cz[lane], 0.f);
    float h1 = fmaxf(P[u * HH + 64 + lane] + Q[v * HH + 64 + lane] + cz[64 + lane], 0.f);
    float p = h0 * w2[lane] + h1 * w2[64 + lane];
    for (int off = 32; off >= 1; off >>= 1) p += __shfl_down(p, off, 64);
    if (lane == 0) {
        float logit = p + b2[0];
        out[NN * 2 + wid] = logit;                               // inv_logit
        out[3 * NN * 2 + wid] = (logit > 0.f) ? 1.f : 0.f;       // inv_bit
    }
}

// ---------------- launch ----------------

extern "C" void kernel_launch(void* const* d_in, const int* in_sizes, int n_in,
                              void* d_out, int out_size, void* d_ws, size_t ws_size,
                              hipStream_t stream) {
    const float* x       = (const float*)d_in[0];
    const float* z       = (const float*)d_in[1];
    const int*   eidx    = (const int*)d_in[2];
    const int*   depth   = (const int*)d_in[3];
    const float* conv1_w = (const float*)d_in[4];
    const float* conv1_b = (const float*)d_in[5];
    const float* conv2_w = (const float*)d_in[6];
    const float* conv2_b = (const float*)d_in[7];
    const float* np1_w   = (const float*)d_in[8];
    const float* np1_b   = (const float*)d_in[9];
    const float* np2_w   = (const float*)d_in[10];
    const float* np2_b   = (const float*)d_in[11];
    const float* src_w   = (const float*)d_in[12];
    const float* tgt_w   = (const float*)d_in[13];
    const float* inv1_w  = (const float*)d_in[14];
    const float* inv1_b  = (const float*)d_in[15];
    const float* inv2_w  = (const float*)d_in[16];
    const float* inv2_b  = (const float*)d_in[17];
    float* out = (float*)d_out;
    float* wsf = (float*)d_ws;

    const int NH = NN * HH;
    float* b0 = wsf;             // xw1/xw2, later Ht
    float* b1 = wsf + (size_t)NH;        // agg, later Hs
    float* b2 = wsf + 2 * (size_t)NH;    // h1/h2, later P
    float* b3 = wsf + 3 * (size_t)NH;    // t, later Q
    float* b4 = wsf + 4 * (size_t)NH;    // h3
    float* T  = wsf + 5 * (size_t)NH;    // 7 x 16384 transposed weights
    float* c1 = T + 7 * 16384;
    float* cz = c1 + 128;
    float* degf = cz + 128;
    float* rsq  = degf + NN;
    float* deg  = rsq + NN;
    int*   cnt  = (int*)(deg + NN);
    float* pval = (float*)(cnt + NN);
    int*   pidx = (int*)(pval + NN * 16);
    int*   tidx = pidx + NN * 16;

    const int* esrc = eidx;
    const int* edst = eidx + EE;

    hipMemsetAsync(deg, 0, NN * sizeof(float), stream);
    hipMemsetAsync(b1, 0, (size_t)NH * sizeof(float), stream);
    k_prep<<<dim3(64, 8), 256, 0, stream>>>(conv2_w, np1_w, np2_w, src_w, tgt_w, inv1_w,
                                            np1_b, inv1_b, z, T, c1, cz);
    k_deg<<<EE / 256, 256, 0, stream>>>(edst, deg);
    k_rsq<<<NN / 256, 256, 0, stream>>>(deg, degf, rsq);
    k_xw1<<<NH / 256, 256, 0, stream>>>(x, conv1_w, b0);
    k_scatter<<<(EE / 2), 256, 0, stream>>>(esrc, edst, rsq, b0, b1);      // E*H/256 = 65536
    k_bias_act<<<NH / 256, 256, 0, stream>>>(b1, b0, degf, conv1_b, b2);   // h1
    k_gemm128<<<256, 256, 0, stream>>>(b2, T + 0 * 16384, nullptr, b0, 0); // xw2
    hipMemsetAsync(b1, 0, (size_t)NH * sizeof(float), stream);
    k_scatter<<<(EE / 2), 256, 0, stream>>>(esrc, edst, rsq, b0, b1);
    k_bias_act<<<NH / 256, 256, 0, stream>>>(b1, b0, degf, conv2_b, b2);   // h2
    k_gemm128<<<256, 256, 0, stream>>>(b2, T + 1 * 16384, c1, b3, 1);      // t = relu(h2@np1h^T + c1)
    k_gemm128<<<256, 256, 0, stream>>>(b3, T + 2 * 16384, np2_b, b4, 0);   // h3
    k_gemm128<<<256, 256, 0, stream>>>(b4, T + 4 * 16384, nullptr, b0, 0); // Ht = h3@tgt^T
    k_gemm128<<<256, 256, 0, stream>>>(b4, T + 3 * 16384, nullptr, b1, 0); // Hs = h3@src^T
    k_gemm128<<<256, 256, 0, stream>>>(b4, T + 5 * 16384, nullptr, b2, 0); // P = h3@inv1a^T
    k_gemm128<<<256, 256, 0, stream>>>(b4, T + 6 * 16384, nullptr, b3, 0); // Q = h3@inv1b^T
    k_cnt_valid<<<NN / 256, 256, 0, stream>>>(depth, x, cnt, out);
    k_top2_stage1<<<dim3(NN / 64, 8), 256, 0, stream>>>(b0, b1, cnt, pval, pidx);
    k_top2_merge<<<NN / 256, 256, 0, stream>>>(pval, pidx, out, tidx);
    k_inv<<<(NN * 2 * 64) / 256, 256, 0, stream>>>(b2, b3, cz, inv2_w, inv2_b, tidx, out);
}

// Round 2
// 542.618 us; speedup vs baseline: 1.1582x; 1.1582x over previous
//
#include <hip/hip_runtime.h>

#define NN 8192
#define EE 131072
#define HH 128
#define NEGV -1.0e30f
#define SEG 512
#define NSEG (NN / SEG)   // 16
#define VT 128
#define UT 128

// ---------------- GCN helpers ----------------

__global__ __launch_bounds__(256) void k_deg(const int* __restrict__ dst, float* __restrict__ deg) {
    int t = blockIdx.x * 256 + threadIdx.x;
    if (t < EE) atomicAdd(&deg[dst[t]], 1.0f);
}

__global__ __launch_bounds__(256) void k_rsq(const float* __restrict__ deg, float* __restrict__ degf,
                                             float* __restrict__ rsq) {
    int t = blockIdx.x * 256 + threadIdx.x;
    if (t < NN) {
        float d = deg[t] + 1.0f;   // +1 self loop
        degf[t] = d;
        rsq[t] = (float)(1.0 / sqrt((double)d));
    }
}

__global__ __launch_bounds__(256) void k_xw1(const float* __restrict__ x, const float* __restrict__ w,
                                             float* __restrict__ out) {
    int t = blockIdx.x * 256 + threadIdx.x;   // N*H threads
    int i = t >> 7, j = t & 127;
    out[t] = x[i * 2] * w[j * 2] + x[i * 2 + 1] * w[j * 2 + 1];
}

__global__ __launch_bounds__(256) void k_scatter(const int* __restrict__ src, const int* __restrict__ dst,
                                                 const float* __restrict__ rsq, const float* __restrict__ xw,
                                                 float* __restrict__ agg) {
    int t = blockIdx.x * 256 + threadIdx.x;   // E*H threads
    int e = t >> 7, j = t & 127;
    int s = src[e], d = dst[e];
    atomicAdd(&agg[d * HH + j], rsq[s] * rsq[d] * xw[s * HH + j]);
}

__global__ __launch_bounds__(256) void k_bias_act(const float* __restrict__ agg, const float* __restrict__ xw,
                                                  const float* __restrict__ degf, const float* __restrict__ b,
                                                  float* __restrict__ out) {
    int t = blockIdx.x * 256 + threadIdx.x;   // N*H
    int i = t >> 7, j = t & 127;
    float v = agg[t] + xw[t] / degf[i] + b[j];
    out[t] = fmaxf(v, 0.0f);
}

// ---------------- weight prep: transposes + folded-z biases ----------------
// T holds 7 transposed 128x128 mats: 0 conv2, 1 np1(h-part), 2 np2, 3 src, 4 tgt, 5 inv1(h_u), 6 inv1(h_v)

__global__ __launch_bounds__(256) void k_prep(const float* __restrict__ conv2_w, const float* __restrict__ np1_w,
                                              const float* __restrict__ np2_w, const float* __restrict__ src_w,
                                              const float* __restrict__ tgt_w, const float* __restrict__ inv1_w,
                                              const float* __restrict__ np1_b, const float* __restrict__ inv1_b,
                                              const float* __restrict__ z, float* __restrict__ T,
                                              float* __restrict__ c1, float* __restrict__ cz) {
    int y = blockIdx.y;
    if (y < 7) {
        int t = blockIdx.x * 256 + threadIdx.x;   // 16384 per matrix
        int j = t >> 7, k = t & 127;
        const float* W; int stride, off;
        switch (y) {
            case 0:  W = conv2_w; stride = 128; off = 0;   break;
            case 1:  W = np1_w;   stride = 256; off = 0;   break;
            case 2:  W = np2_w;   stride = 128; off = 0;   break;
            case 3:  W = src_w;   stride = 128; off = 0;   break;
            case 4:  W = tgt_w;   stride = 128; off = 0;   break;
            case 5:  W = inv1_w;  stride = 384; off = 0;   break;
            default: W = inv1_w;  stride = 384; off = 128; break;
        }
        T[y * 16384 + k * 128 + j] = W[j * stride + off + k];
    } else if (blockIdx.x == 0) {
        int tid = threadIdx.x;
        if (tid < 128) {
            float s = np1_b[tid];
            for (int k = 0; k < 128; k++) s += z[k] * np1_w[tid * 256 + 128 + k];
            c1[tid] = s;
        } else {
            int j = tid - 128;
            float s = inv1_b[j];
            for (int k = 0; k < 128; k++) s += z[k] * inv1_w[j * 384 + 256 + k];
            cz[j] = s;
        }
    }
}

// ---------------- generic [8192x128] @ WT[128x128] (+bias)(+relu) ----------------

__global__ __launch_bounds__(256) void k_gemm128(const float* __restrict__ A, const float* __restrict__ WT,
                                                 const float* __restrict__ bias, float* __restrict__ out,
                                                 int relu) {
    __shared__ float As[32][33];
    __shared__ float Bs[32][128];
    int tid = threadIdx.x;
    int tx = tid & 31, ty = tid >> 5;
    int row0 = blockIdx.x * 32;
    float acc[4][4] = {};
    for (int k0 = 0; k0 < 128; k0 += 32) {
        {
            int r = tid >> 3, k = (tid & 7) << 2;
            float4 v = *(const float4*)&A[(row0 + r) * HH + k0 + k];
            As[r][k] = v.x; As[r][k + 1] = v.y; As[r][k + 2] = v.z; As[r][k + 3] = v.w;
        }
#pragma unroll
        for (int i = 0; i < 4; i++) {
            int kk = (tid >> 5) + i * 8;
            int c = (tid & 31) << 2;
            *(float4*)&Bs[kk][c] = *(const float4*)&WT[(k0 + kk) * HH + c];
        }
        __syncthreads();
#pragma unroll 8
        for (int kk = 0; kk < 32; kk++) {
            float a0 = As[ty * 4 + 0][kk], a1 = As[ty * 4 + 1][kk];
            float a2 = As[ty * 4 + 2][kk], a3 = As[ty * 4 + 3][kk];
            float4 b = *(const float4*)&Bs[kk][tx * 4];
            acc[0][0] = fmaf(a0, b.x, acc[0][0]); acc[0][1] = fmaf(a0, b.y, acc[0][1]);
            acc[0][2] = fmaf(a0, b.z, acc[0][2]); acc[0][3] = fmaf(a0, b.w, acc[0][3]);
            acc[1][0] = fmaf(a1, b.x, acc[1][0]); acc[1][1] = fmaf(a1, b.y, acc[1][1]);
            acc[1][2] = fmaf(a1, b.z, acc[1][2]); acc[1][3] = fmaf(a1, b.w, acc[1][3]);
            acc[2][0] = fmaf(a2, b.x, acc[2][0]); acc[2][1] = fmaf(a2, b.y, acc[2][1]);
            acc[2][2] = fmaf(a2, b.z, acc[2][2]); acc[2][3] = fmaf(a2, b.w, acc[2][3]);
            acc[3][0] = fmaf(a3, b.x, acc[3][0]); acc[3][1] = fmaf(a3, b.y, acc[3][1]);
            acc[3][2] = fmaf(a3, b.z, acc[3][2]); acc[3][3] = fmaf(a3, b.w, acc[3][3]);
        }
        __syncthreads();
    }
#pragma unroll
    for (int i = 0; i < 4; i++) {
        float4 v = make_float4(acc[i][0], acc[i][1], acc[i][2], acc[i][3]);
        if (bias) {
            v.x += bias[tx * 4]; v.y += bias[tx * 4 + 1];
            v.z += bias[tx * 4 + 2]; v.w += bias[tx * 4 + 3];
        }
        if (relu) {
            v.x = fmaxf(v.x, 0.f); v.y = fmaxf(v.y, 0.f);
            v.z = fmaxf(v.z, 0.f); v.w = fmaxf(v.w, 0.f);
        }
        *(float4*)&out[(row0 + ty * 4 + i) * HH + tx * 4] = v;
    }
}

// Batched variant: 4 projections of the same A (Ht/Hs/P/Q), selected by blockIdx.y
__global__ __launch_bounds__(256) void k_gemm128x4(const float* __restrict__ A, const float* __restrict__ T,
                                                   float* __restrict__ o0, float* __restrict__ o1,
                                                   float* __restrict__ o2, float* __restrict__ o3) {
    __shared__ float As[32][33];
    __shared__ float Bs[32][128];
    int which = blockIdx.y;
    const float* WT; float* out;
    switch (which) {
        case 0:  WT = T + 4 * 16384; out = o0; break;   // Ht = h3 @ tgt^T
        case 1:  WT = T + 3 * 16384; out = o1; break;   // Hs = h3 @ src^T
        case 2:  WT = T + 5 * 16384; out = o2; break;   // P
        default: WT = T + 6 * 16384; out = o3; break;   // Q
    }
    int tid = threadIdx.x;
    int tx = tid & 31, ty = tid >> 5;
    int row0 = blockIdx.x * 32;
    float acc[4][4] = {};
    for (int k0 = 0; k0 < 128; k0 += 32) {
        {
            int r = tid >> 3, k = (tid & 7) << 2;
            float4 v = *(const float4*)&A[(row0 + r) * HH + k0 + k];
            As[r][k] = v.x; As[r][k + 1] = v.y; As[r][k + 2] = v.z; As[r][k + 3] = v.w;
        }
#pragma unroll
        for (int i = 0; i < 4; i++) {
            int kk = (tid >> 5) + i * 8;
            int c = (tid & 31) << 2;
            *(float4*)&Bs[kk][c] = *(const float4*)&WT[(k0 + kk) * HH + c];
        }
        __syncthreads();
#pragma unroll 8
        for (int kk = 0; kk < 32; kk++) {
            float a0 = As[ty * 4 + 0][kk], a1 = As[ty * 4 + 1][kk];
            float a2 = As[ty * 4 + 2][kk], a3 = As[ty * 4 + 3][kk];
            float4 b = *(const float4*)&Bs[kk][tx * 4];
            acc[0][0] = fmaf(a0, b.x, acc[0][0]); acc[0][1] = fmaf(a0, b.y, acc[0][1]);
            acc[0][2] = fmaf(a0, b.z, acc[0][2]); acc[0][3] = fmaf(a0, b.w, acc[0][3]);
            acc[1][0] = fmaf(a1, b.x, acc[1][0]); acc[1][1] = fmaf(a1, b.y, acc[1][1]);
            acc[1][2] = fmaf(a1, b.z, acc[1][2]); acc[1][3] = fmaf(a1, b.w, acc[1][3]);
            acc[2][0] = fmaf(a2, b.x, acc[2][0]); acc[2][1] = fmaf(a2, b.y, acc[2][1]);
            acc[2][2] = fmaf(a2, b.z, acc[2][2]); acc[2][3] = fmaf(a2, b.w, acc[2][3]);
            acc[3][0] = fmaf(a3, b.x, acc[3][0]); acc[3][1] = fmaf(a3, b.y, acc[3][1]);
            acc[3][2] = fmaf(a3, b.z, acc[3][2]); acc[3][3] = fmaf(a3, b.w, acc[3][3]);
        }
        __syncthreads();
    }
#pragma unroll
    for (int i = 0; i < 4; i++) {
        float4 v = make_float4(acc[i][0], acc[i][1], acc[i][2], acc[i][3]);
        *(float4*)&out[(row0 + ty * 4 + i) * HH + tx * 4] = v;
    }
}

// ---------------- candidate counts + valid flags ----------------

__global__ __launch_bounds__(256) void k_cnt_valid(const int* __restrict__ depth, const float* __restrict__ x,
                                                   int* __restrict__ cnt, float* __restrict__ out) {
    int v = blockIdx.x * 256 + threadIdx.x;
    if (v >= NN) return;
    int limit = depth[v] + 1;   // depth[v]-1+DEPTH_PERTURB
    int lo = 0, hi = NN;
    while (lo < hi) { int mid = (lo + hi) >> 1; if (depth[mid] <= limit) lo = mid + 1; else hi = mid; }
    cnt[v] = lo;
    int type = (int)(x[v * 2] + 0.5f);
    bool tv = (depth[v] >= 1) && (type != 0);
    out[4 * NN * 2 + v * 2 + 0] = (tv && lo >= 1) ? 1.0f : 0.0f;
    out[4 * NN * 2 + v * 2 + 1] = (tv && type == 2 && lo >= 2) ? 1.0f : 0.0f;
}

// ---------------- fused masked GEMM + top-2 (stage 1) ----------------
// 128x128 block tile, 8x8 per-thread register tile, k-major LDS chunks of 32.

__global__ __launch_bounds__(256, 3) void k_top2_stage1(const float* __restrict__ Ht,
                                                        const float* __restrict__ Hs,
                                                        const int* __restrict__ cnt,
                                                        float* __restrict__ pval, int* __restrict__ pidx) {
    __shared__ float HtS[32 * 128];   // [k][v], k-major
    __shared__ float HsS[32 * 128];   // [k][u], k-major
    __shared__ int cntS[128];
    int tid = threadIdx.x;
    int v0 = blockIdx.x * VT;
    int seg = blockIdx.y;
    int useg0 = seg * SEG;
    if (tid < 128) cntS[tid] = cnt[v0 + tid];
    __syncthreads();
    int cmax = cntS[127];   // depth sorted -> cnt nondecreasing
    if (useg0 >= cmax) {    // whole segment masked for every row in block
        if (tid < 128) {
            int o = ((v0 + tid) * NSEG + seg) * 2;
            pval[o] = NEGV;     pidx[o] = useg0;
            pval[o + 1] = NEGV; pidx[o + 1] = useg0 + 1;
        }
        return;
    }
    int tx = tid & 15, ty = tid >> 4;
    // per-thread rows: {4ty..4ty+3} and {64+4ty..64+4ty+3}; cols likewise with tx
    int creg[8];
#pragma unroll
    for (int i = 0; i < 8; i++) creg[i] = cntS[((i >> 2) << 6) + 4 * ty + (i & 3)];
    float t1v[8], t2v[8]; int t1i[8], t2i[8];
#pragma unroll
    for (int i = 0; i < 8; i++) { t1v[i] = NEGV; t2v[i] = NEGV; t1i[i] = 0x7fffffff; t2i[i] = 0x7fffffff; }

    int uend = useg0 + SEG; if (uend > cmax) uend = cmax;
    for (int ub = useg0; ub < uend; ub += UT) {
        float acc[8][8] = {};
        for (int k0 = 0; k0 < 128; k0 += 32) {
            __syncthreads();
            // stage k-chunk of Ht and Hs, transposed to k-major. Lanes cover
            // consecutive rows -> ds_write banks 2-way (free); global reads are
            // 512B-strided float4 (L1/L2 resident).
#pragma unroll
            for (int p = 0; p < 4; p++) {
                int q = p * 256 + tid;          // 0..1023
                int r = q & 127;                // tile row
                int kq = q >> 7;                // 0..7 (float4 group within 32-k chunk)
                float4 va = *(const float4*)&Ht[(size_t)(v0 + r) * HH + k0 + 4 * kq];
                HtS[(4 * kq + 0) * 128 + r] = va.x;
                HtS[(4 * kq + 1) * 128 + r] = va.y;
                HtS[(4 * kq + 2) * 128 + r] = va.z;
                HtS[(4 * kq + 3) * 128 + r] = va.w;
                float4 vb = *(const float4*)&Hs[(size_t)(ub + r) * HH + k0 + 4 * kq];
                HsS[(4 * kq + 0) * 128 + r] = vb.x;
                HsS[(4 * kq + 1) * 128 + r] = vb.y;
                HsS[(4 * kq + 2) * 128 + r] = vb.z;
                HsS[(4 * kq + 3) * 128 + r] = vb.w;
            }
            __syncthreads();
#pragma unroll 4
            for (int kk = 0; kk < 32; kk++) {
                float4 a0 = *(const float4*)&HtS[kk * 128 + 4 * ty];
                float4 a1 = *(const float4*)&HtS[kk * 128 + 64 + 4 * ty];
                float4 b0 = *(const float4*)&HsS[kk * 128 + 4 * tx];
                float4 b1 = *(const float4*)&HsS[kk * 128 + 64 + 4 * tx];
                float av[8] = {a0.x, a0.y, a0.z, a0.w, a1.x, a1.y, a1.z, a1.w};
                float bv[8] = {b0.x, b0.y, b0.z, b0.w, b1.x, b1.y, b1.z, b1.w};
#pragma unroll
                for (int i = 0; i < 8; i++)
#pragma unroll
                    for (int j = 0; j < 8; j++)
                        acc[i][j] = fmaf(av[i], bv[j], acc[i][j]);
            }
        }
        // fold this u-tile into per-thread running top-2
#pragma unroll
        for (int i = 0; i < 8; i++) {
            int c = creg[i];
#pragma unroll
            for (int j = 0; j < 8; j++) {
                int u = ub + ((j >> 2) << 6) + 4 * tx + (j & 3);
                float val = (u < c) ? acc[i][j] : NEGV;   // masked: NEG with real index
                if (val > t1v[i] || (val == t1v[i] && u < t1i[i])) {
                    t2v[i] = t1v[i]; t2i[i] = t1i[i]; t1v[i] = val; t1i[i] = u;
                } else if (val > t2v[i] || (val == t2v[i] && u < t2i[i])) {
                    t2v[i] = val; t2i[i] = u;
                }
            }
        }
    }
    __syncthreads();
    // cross-thread merge: reuse tiles as (val,idx) buffers, q-major to keep reads conflict-free
    float* mv = HsS;
    int* mi = (int*)HtS;
#pragma unroll
    for (int i = 0; i < 8; i++) {
        int row = ((i >> 2) << 6) + 4 * ty + (i & 3);
        mv[(tx * 2 + 0) * 128 + row] = t1v[i]; mi[(tx * 2 + 0) * 128 + row] = t1i[i];
        mv[(tx * 2 + 1) * 128 + row] = t2v[i]; mi[(tx * 2 + 1) * 128 + row] = t2i[i];
    }
    __syncthreads();
    if (tid < 128) {
        float v1 = NEGV, v2 = NEGV; int i1 = 0x7fffffff, i2 = 0x7fffffff;
        for (int q = 0; q < 32; q++) {
            float val = mv[q * 128 + tid]; int idx = mi[q * 128 + tid];
            if (val > v1 || (val == v1 && idx < i1)) { v2 = v1; i2 = i1; v1 = val; i1 = idx; }
            else if (val > v2 || (val == v2 && idx < i2)) { v2 = val; i2 = idx; }
        }
        int o = ((v0 + tid) * NSEG + seg) * 2;
        pval[o] = v1;     pidx[o] = i1;
        pval[o + 1] = v2; pidx[o + 1] = i2;
    }
}

// ---------------- stage 2: merge segment partials, emit top_vals/top_idx ----------------

__global__ __launch_bounds__(256) void k_top2_merge(const float* __restrict__ pval, const int* __restrict__ pidx,
                                                    float* __restrict__ out, int* __restrict__ tidx) {
    int v = blockIdx.x * 256 + threadIdx.x;
    if (v >= NN) return;
    float v1 = NEGV, v2 = NEGV; int i1 = 0x7fffffff, i2 = 0x7fffffff;
    for (int t = 0; t < NSEG * 2; t++) {
        float val = pval[v * (NSEG * 2) + t]; int idx = pidx[v * (NSEG * 2) + t];
        if (val > v1 || (val == v1 && idx < i1)) { v2 = v1; i2 = i1; v1 = val; i1 = idx; }
        else if (val > v2 || (val == v2 && idx < i2)) { v2 = val; i2 = idx; }
    }
    out[v * 2 + 0] = v1; out[v * 2 + 1] = v2;                    // top_vals
    out[2 * NN * 2 + v * 2 + 0] = (float)i1;                     // top_idx
    out[2 * NN * 2 + v * 2 + 1] = (float)i2;
    tidx[v * 2] = i1; tidx[v * 2 + 1] = i2;
}

// ---------------- inversion-bit epilogue: logit = inv2 . relu(P[u]+Q[v]+cz) + b ----------------

__global__ __launch_bounds__(256) void k_inv(const float* __restrict__ P, const float* __restrict__ Q,
                                             const float* __restrict__ cz, const float* __restrict__ w2,
                                             const float* __restrict__ b2, const int* __restrict__ tidx,
                                             float* __restrict__ out) {
    int gid = blockIdx.x * 256 + threadIdx.x;
    int wid = gid >> 6;
    int lane = gid & 63;
    if (wid >= NN * 2) return;
    int v = wid >> 1;
    int u = tidx[wid]; if (u > NN - 1) u = NN - 1; if (u < 0) u = 0;
    float h0 = fmaxf(P[u * HH + lane] + Q[v * HH + lane] + cz[lane], 0.f);
    float h1 = fmaxf(P[u * HH + 64 + lane] + Q[v * HH + 64 + lane] + cz[64 + lane], 0.f);
    float p = h0 * w2[lane] + h1 * w2[64 + lane];
    for (int off = 32; off >= 1; off >>= 1) p += __shfl_down(p, off, 64);
    if (lane == 0) {
        float logit = p + b2[0];
        out[NN * 2 + wid] = logit;                               // inv_logit
        out[3 * NN * 2 + wid] = (logit > 0.f) ? 1.f : 0.f;       // inv_bit
    }
}

// ---------------- launch ----------------

extern "C" void kernel_launch(void* const* d_in, const int* in_sizes, int n_in,
                              void* d_out, int out_size, void* d_ws, size_t ws_size,
                              hipStream_t stream) {
    const float* x       = (const float*)d_in[0];
    const float* z       = (const float*)d_in[1];
    const int*   eidx    = (const int*)d_in[2];
    const int*   depth   = (const int*)d_in[3];
    const float* conv1_w = (const float*)d_in[4];
    const float* conv1_b = (const float*)d_in[5];
    const float* conv2_w = (const float*)d_in[6];
    const float* conv2_b = (const float*)d_in[7];
    const float* np1_w   = (const float*)d_in[8];
    const float* np1_b   = (const float*)d_in[9];
    const float* np2_w   = (const float*)d_in[10];
    const float* np2_b   = (const float*)d_in[11];
    const float* src_w   = (const float*)d_in[12];
    const float* tgt_w   = (const float*)d_in[13];
    const float* inv1_w  = (const float*)d_in[14];
    const float* inv1_b  = (const float*)d_in[15];
    const float* inv2_w  = (const float*)d_in[16];
    const float* inv2_b  = (const float*)d_in[17];
    float* out = (float*)d_out;
    float* wsf = (float*)d_ws;

    const int NH = NN * HH;
    float* b0 = wsf;                     // xw1/xw2, later Ht
    float* b1 = wsf + (size_t)NH;        // agg, later Hs
    float* b2 = wsf + 2 * (size_t)NH;    // h1/h2, later P
    float* b3 = wsf + 3 * (size_t)NH;    // t, later Q
    float* b4 = wsf + 4 * (size_t)NH;    // h3; dead after projections -> partial bufs
    float* T  = wsf + 5 * (size_t)NH;    // 7 x 16384 transposed weights
    float* c1 = T + 7 * 16384;
    float* cz = c1 + 128;
    float* degf = cz + 128;
    float* rsq  = degf + NN;
    float* deg  = rsq + NN;
    int*   cnt  = (int*)(deg + NN);
    // partial top-2 buffers live in b4's space (h3 is dead by stage1 time)
    float* pval = b4;                    // NN * NSEG * 2 = 262144 floats
    int*   pidx = (int*)(b4 + NN * NSEG * 2);
    int*   tidx = (int*)(b4 + 2 * NN * NSEG * 2);

    const int* esrc = eidx;
    const int* edst = eidx + EE;

    hipMemsetAsync(deg, 0, NN * sizeof(float), stream);
    hipMemsetAsync(b1, 0, (size_t)NH * sizeof(float), stream);
    k_prep<<<dim3(64, 8), 256, 0, stream>>>(conv2_w, np1_w, np2_w, src_w, tgt_w, inv1_w,
                                            np1_b, inv1_b, z, T, c1, cz);
    k_deg<<<EE / 256, 256, 0, stream>>>(edst, deg);
    k_rsq<<<NN / 256, 256, 0, stream>>>(deg, degf, rsq);
    k_xw1<<<NH / 256, 256, 0, stream>>>(x, conv1_w, b0);
    k_scatter<<<(EE / 2), 256, 0, stream>>>(esrc, edst, rsq, b0, b1);
    k_bias_act<<<NH / 256, 256, 0, stream>>>(b1, b0, degf, conv1_b, b2);   // h1
    k_gemm128<<<256, 256, 0, stream>>>(b2, T + 0 * 16384, nullptr, b0, 0); // xw2
    hipMemsetAsync(b1, 0, (size_t)NH * sizeof(float), stream);
    k_scatter<<<(EE / 2), 256, 0, stream>>>(esrc, edst, rsq, b0, b1);
    k_bias_act<<<NH / 256, 256, 0, stream>>>(b1, b0, degf, conv2_b, b2);   // h2
    k_gemm128<<<256, 256, 0, stream>>>(b2, T + 1 * 16384, c1, b3, 1);      // t = relu(h2@np1h^T + c1)
    k_gemm128<<<256, 256, 0, stream>>>(b3, T + 2 * 16384, np2_b, b4, 0);   // h3
    k_gemm128x4<<<dim3(256, 4), 256, 0, stream>>>(b4, T, b0, b1, b2, b3);  // Ht, Hs, P, Q
    k_cnt_valid<<<NN / 256, 256, 0, stream>>>(depth, x, cnt, out);
    k_top2_stage1<<<dim3(NN / VT, NSEG), 256, 0, stream>>>(b0, b1, cnt, pval, pidx);
    k_top2_merge<<<NN / 256, 256, 0, stream>>>(pval, pidx, out, tidx);
    k_inv<<<(NN * 2 * 64) / 256, 256, 0, stream>>>(b2, b3, cz, inv2_w, inv2_b, tidx, out);
}

// Round 3
// 394.124 us; speedup vs baseline: 1.5945x; 1.3768x over previous
//
#include <hip/hip_runtime.h>

#define NN 8192
#define EE 131072
#define HH 128
#define NEGV -1.0e30f
#define SEG 256
#define NSEG (NN / SEG)   // 32
#define UT 128

// ---------------- degree (int) ----------------

__global__ __launch_bounds__(256) void k_deg(const int* __restrict__ dst, int* __restrict__ degi) {
    int t = blockIdx.x * 256 + threadIdx.x;
    if (t < EE) atomicAdd(&degi[dst[t]], 1);
}

__global__ __launch_bounds__(256) void k_rsq(const int* __restrict__ degi, float* __restrict__ dinv,
                                             float* __restrict__ rsq) {
    int t = blockIdx.x * 256 + threadIdx.x;
    if (t < NN) {
        double d = (double)(degi[t] + 1);   // +1 self loop
        dinv[t] = (float)(1.0 / d);
        rsq[t] = (float)(1.0 / sqrt(d));
    }
}

// exclusive scan of degi[NN] -> rowptr[NN+1]; single block of 1024, 8 elems/thread
__global__ __launch_bounds__(1024) void k_scan(const int* __restrict__ degi, int* __restrict__ rowptr) {
    __shared__ int ls[1024];
    int tid = threadIdx.x;
    int base = tid * 8;
    int loc[8]; int s = 0;
#pragma unroll
    for (int i = 0; i < 8; i++) { loc[i] = s; s += degi[base + i]; }
    ls[tid] = s; __syncthreads();
    int tot = s;
    for (int d = 1; d < 1024; d <<= 1) {
        int v = (tid >= d) ? ls[tid - d] : 0;
        __syncthreads();
        ls[tid] += v;
        __syncthreads();
    }
    int pre = ls[tid] - tot;
#pragma unroll
    for (int i = 0; i < 8; i++) rowptr[base + i] = pre + loc[i];
    if (tid == 1023) rowptr[NN] = pre + tot;
}

__global__ __launch_bounds__(256) void k_fill(const int* __restrict__ src, const int* __restrict__ dst,
                                              const int* __restrict__ rowptr, int* __restrict__ cursor,
                                              int* __restrict__ ecsr) {
    int t = blockIdx.x * 256 + threadIdx.x;
    if (t < EE) {
        int d = dst[t];
        int pos = atomicAdd(&cursor[d], 1);
        ecsr[rowptr[d] + pos] = src[t];
    }
}

// ---------------- GCN: xw for conv1, gather-aggregate (fused bias+relu) ----------------

__global__ __launch_bounds__(256) void k_xw1(const float* __restrict__ x, const float* __restrict__ w,
                                             float* __restrict__ out) {
    int t = blockIdx.x * 256 + threadIdx.x;   // N*H threads
    int i = t >> 7, j = t & 127;
    out[t] = x[i * 2] * w[j * 2] + x[i * 2 + 1] * w[j * 2 + 1];
}

__global__ __launch_bounds__(256) void k_gather(const int* __restrict__ rowptr, const int* __restrict__ ecsr,
                                                const float* __restrict__ rsq, const float* __restrict__ dinv,
                                                const float* __restrict__ xw, const float* __restrict__ bias,
                                                float* __restrict__ out) {
    int g = blockIdx.x * 256 + threadIdx.x;
    int d = g >> 6, lane = g & 63;
    if (d >= NN) return;
    int s0 = rowptr[d], s1 = rowptr[d + 1];
    float rd = rsq[d];
    float a0 = 0.f, a1 = 0.f;
    for (int sl = s0; sl < s1; sl++) {
        int s = ecsr[sl];                       // wave-uniform scalar load
        float f = rsq[s] * rd;
        a0 = fmaf(f, xw[s * HH + lane], a0);    // coalesced 256B row segment
        a1 = fmaf(f, xw[s * HH + 64 + lane], a1);
    }
    float di = dinv[d];
    a0 = fmaf(xw[d * HH + lane], di, a0) + bias[lane];
    a1 = fmaf(xw[d * HH + 64 + lane], di, a1) + bias[64 + lane];
    out[d * HH + lane] = fmaxf(a0, 0.f);
    out[d * HH + 64 + lane] = fmaxf(a1, 0.f);
}

// ---------------- weight prep: transposes + folded-z biases ----------------
// T holds 7 transposed 128x128 mats: 0 conv2, 1 np1(h-part), 2 np2, 3 src, 4 tgt, 5 inv1(h_u), 6 inv1(h_v)

__global__ __launch_bounds__(256) void k_prep(const float* __restrict__ conv2_w, const float* __restrict__ np1_w,
                                              const float* __restrict__ np2_w, const float* __restrict__ src_w,
                                              const float* __restrict__ tgt_w, const float* __restrict__ inv1_w,
                                              const float* __restrict__ np1_b, const float* __restrict__ inv1_b,
                                              const float* __restrict__ z, float* __restrict__ T,
                                              float* __restrict__ c1, float* __restrict__ cz) {
    int y = blockIdx.y;
    if (y < 7) {
        int t = blockIdx.x * 256 + threadIdx.x;   // 16384 per matrix
        int j = t >> 7, k = t & 127;
        const float* W; int stride, off;
        switch (y) {
            case 0:  W = conv2_w; stride = 128; off = 0;   break;
            case 1:  W = np1_w;   stride = 256; off = 0;   break;
            case 2:  W = np2_w;   stride = 128; off = 0;   break;
            case 3:  W = src_w;   stride = 128; off = 0;   break;
            case 4:  W = tgt_w;   stride = 128; off = 0;   break;
            case 5:  W = inv1_w;  stride = 384; off = 0;   break;
            default: W = inv1_w;  stride = 384; off = 128; break;
        }
        T[y * 16384 + k * 128 + j] = W[j * stride + off + k];
    } else if (blockIdx.x == 0) {
        int tid = threadIdx.x;
        if (tid < 128) {
            float s = np1_b[tid];
            for (int k = 0; k < 128; k++) s += z[k] * np1_w[tid * 256 + 128 + k];
            c1[tid] = s;
        } else {
            int j = tid - 128;
            float s = inv1_b[j];
            for (int k = 0; k < 128; k++) s += z[k] * inv1_w[j * 384 + 256 + k];
            cz[j] = s;
        }
    }
}

// ---------------- generic [8192x128] @ WT[128x128] (+bias)(+relu) ----------------

__global__ __launch_bounds__(256) void k_gemm128(const float* __restrict__ A, const float* __restrict__ WT,
                                                 const float* __restrict__ bias, float* __restrict__ out,
                                                 int relu) {
    __shared__ float As[32][33];
    __shared__ float Bs[32][128];
    int tid = threadIdx.x;
    int tx = tid & 31, ty = tid >> 5;
    int row0 = blockIdx.x * 32;
    float acc[4][4] = {};
    for (int k0 = 0; k0 < 128; k0 += 32) {
        {
            int r = tid >> 3, k = (tid & 7) << 2;
            float4 v = *(const float4*)&A[(row0 + r) * HH + k0 + k];
            As[r][k] = v.x; As[r][k + 1] = v.y; As[r][k + 2] = v.z; As[r][k + 3] = v.w;
        }
#pragma unroll
        for (int i = 0; i < 4; i++) {
            int kk = (tid >> 5) + i * 8;
            int c = (tid & 31) << 2;
            *(float4*)&Bs[kk][c] = *(const float4*)&WT[(k0 + kk) * HH + c];
        }
        __syncthreads();
#pragma unroll 8
        for (int kk = 0; kk < 32; kk++) {
            float a0 = As[ty * 4 + 0][kk], a1 = As[ty * 4 + 1][kk];
            float a2 = As[ty * 4 + 2][kk], a3 = As[ty * 4 + 3][kk];
            float4 b = *(const float4*)&Bs[kk][tx * 4];
            acc[0][0] = fmaf(a0, b.x, acc[0][0]); acc[0][1] = fmaf(a0, b.y, acc[0][1]);
            acc[0][2] = fmaf(a0, b.z, acc[0][2]); acc[0][3] = fmaf(a0, b.w, acc[0][3]);
            acc[1][0] = fmaf(a1, b.x, acc[1][0]); acc[1][1] = fmaf(a1, b.y, acc[1][1]);
            acc[1][2] = fmaf(a1, b.z, acc[1][2]); acc[1][3] = fmaf(a1, b.w, acc[1][3]);
            acc[2][0] = fmaf(a2, b.x, acc[2][0]); acc[2][1] = fmaf(a2, b.y, acc[2][1]);
            acc[2][2] = fmaf(a2, b.z, acc[2][2]); acc[2][3] = fmaf(a2, b.w, acc[2][3]);
            acc[3][0] = fmaf(a3, b.x, acc[3][0]); acc[3][1] = fmaf(a3, b.y, acc[3][1]);
            acc[3][2] = fmaf(a3, b.z, acc[3][2]); acc[3][3] = fmaf(a3, b.w, acc[3][3]);
        }
        __syncthreads();
    }
#pragma unroll
    for (int i = 0; i < 4; i++) {
        float4 v = make_float4(acc[i][0], acc[i][1], acc[i][2], acc[i][3]);
        if (bias) {
            v.x += bias[tx * 4]; v.y += bias[tx * 4 + 1];
            v.z += bias[tx * 4 + 2]; v.w += bias[tx * 4 + 3];
        }
        if (relu) {
            v.x = fmaxf(v.x, 0.f); v.y = fmaxf(v.y, 0.f);
            v.z = fmaxf(v.z, 0.f); v.w = fmaxf(v.w, 0.f);
        }
        *(float4*)&out[(row0 + ty * 4 + i) * HH + tx * 4] = v;
    }
}

// Batched variant: 4 projections of the same A (Ht/Hs/P/Q), selected by blockIdx.y
__global__ __launch_bounds__(256) void k_gemm128x4(const float* __restrict__ A, const float* __restrict__ T,
                                                   float* __restrict__ o0, float* __restrict__ o1,
                                                   float* __restrict__ o2, float* __restrict__ o3) {
    __shared__ float As[32][33];
    __shared__ float Bs[32][128];
    int which = blockIdx.y;
    const float* WT; float* out;
    switch (which) {
        case 0:  WT = T + 4 * 16384; out = o0; break;   // Ht = h3 @ tgt^T
        case 1:  WT = T + 3 * 16384; out = o1; break;   // Hs = h3 @ src^T
        case 2:  WT = T + 5 * 16384; out = o2; break;   // P
        default: WT = T + 6 * 16384; out = o3; break;   // Q
    }
    int tid = threadIdx.x;
    int tx = tid & 31, ty = tid >> 5;
    int row0 = blockIdx.x * 32;
    float acc[4][4] = {};
    for (int k0 = 0; k0 < 128; k0 += 32) {
        {
            int r = tid >> 3, k = (tid & 7) << 2;
            float4 v = *(const float4*)&A[(row0 + r) * HH + k0 + k];
            As[r][k] = v.x; As[r][k + 1] = v.y; As[r][k + 2] = v.z; As[r][k + 3] = v.w;
        }
#pragma unroll
        for (int i = 0; i < 4; i++) {
            int kk = (tid >> 5) + i * 8;
            int c = (tid & 31) << 2;
            *(float4*)&Bs[kk][c] = *(const float4*)&WT[(k0 + kk) * HH + c];
        }
        __syncthreads();
#pragma unroll 8
        for (int kk = 0; kk < 32; kk++) {
            float a0 = As[ty * 4 + 0][kk], a1 = As[ty * 4 + 1][kk];
            float a2 = As[ty * 4 + 2][kk], a3 = As[ty * 4 + 3][kk];
            float4 b = *(const float4*)&Bs[kk][tx * 4];
            acc[0][0] = fmaf(a0, b.x, acc[0][0]); acc[0][1] = fmaf(a0, b.y, acc[0][1]);
            acc[0][2] = fmaf(a0, b.z, acc[0][2]); acc[0][3] = fmaf(a0, b.w, acc[0][3]);
            acc[1][0] = fmaf(a1, b.x, acc[1][0]); acc[1][1] = fmaf(a1, b.y, acc[1][1]);
            acc[1][2] = fmaf(a1, b.z, acc[1][2]); acc[1][3] = fmaf(a1, b.w, acc[1][3]);
            acc[2][0] = fmaf(a2, b.x, acc[2][0]); acc[2][1] = fmaf(a2, b.y, acc[2][1]);
            acc[2][2] = fmaf(a2, b.z, acc[2][2]); acc[2][3] = fmaf(a2, b.w, acc[2][3]);
            acc[3][0] = fmaf(a3, b.x, acc[3][0]); acc[3][1] = fmaf(a3, b.y, acc[3][1]);
            acc[3][2] = fmaf(a3, b.z, acc[3][2]); acc[3][3] = fmaf(a3, b.w, acc[3][3]);
        }
        __syncthreads();
    }
#pragma unroll
    for (int i = 0; i < 4; i++) {
        float4 v = make_float4(acc[i][0], acc[i][1], acc[i][2], acc[i][3]);
        *(float4*)&out[(row0 + ty * 4 + i) * HH + tx * 4] = v;
    }
}

// ---------------- candidate counts + valid flags ----------------

__global__ __launch_bounds__(256) void k_cnt_valid(const int* __restrict__ depth, const float* __restrict__ x,
                                                   int* __restrict__ cnt, float* __restrict__ out) {
    int v = blockIdx.x * 256 + threadIdx.x;
    if (v >= NN) return;
    int limit = depth[v] + 1;   // depth[v]-1+DEPTH_PERTURB
    int lo = 0, hi = NN;
    while (lo < hi) { int mid = (lo + hi) >> 1; if (depth[mid] <= limit) lo = mid + 1; else hi = mid; }
    cnt[v] = lo;
    int type = (int)(x[v * 2] + 0.5f);
    bool tv = (depth[v] >= 1) && (type != 0);
    out[4 * NN * 2 + v * 2 + 0] = (tv && lo >= 1) ? 1.0f : 0.0f;
    out[4 * NN * 2 + v * 2 + 1] = (tv && type == 2 && lo >= 2) ? 1.0f : 0.0f;
}

// ---------------- active tile list (one wave) ----------------

__global__ __launch_bounds__(64) void k_tiles(const int* __restrict__ cnt, int* __restrict__ nact,
                                              int* __restrict__ tlist, int* __restrict__ ntiles) {
    int lane = threadIdx.x;   // 0..63, one per v0-block
    int cmax = cnt[lane * 128 + 127];
    int n = (cmax + SEG - 1) / SEG;
    nact[lane] = n;
    int x = n;
    for (int off = 1; off < 64; off <<= 1) {
        int y = __shfl_up(x, off, 64);
        if (lane >= off) x += y;
    }
    int base = x - n;
    for (int s = 0; s < n; s++) tlist[base + s] = (lane << 8) | s;
    if (lane == 63) *ntiles = x;
}

// ---------------- fused masked GEMM + top-2 (stage 1, persistent blocks) ----------------
// 128x128 u-tiles, 8x8 per-thread register tile, k-major LDS chunks of 32 (stride 132).

__global__ __launch_bounds__(256, 3) void k_top2_stage1(const float* __restrict__ Ht,
                                                        const float* __restrict__ Hs,
                                                        const int* __restrict__ cnt,
                                                        const int* __restrict__ tlist,
                                                        const int* __restrict__ ntiles,
                                                        int* __restrict__ tctr,
                                                        float* __restrict__ pval, int* __restrict__ pidx) {
    __shared__ float HtS[32 * 132];   // [k][v], k-major, pad 132
    __shared__ float HsS[32 * 132];   // [k][u]
    __shared__ int cntS[128];
    __shared__ int tsh;
    int tid = threadIdx.x;
    int tx = tid & 15, ty = tid >> 4;
    int nt = *ntiles;
    for (;;) {
        if (tid == 0) tsh = atomicAdd(tctr, 1);
        __syncthreads();
        int t = tsh;
        __syncthreads();
        if (t >= nt) return;
        int code = tlist[t];
        int v0 = (code >> 8) * 128;
        int seg = code & 255;
        int ub0 = seg * SEG;
        if (tid < 128) cntS[tid] = cnt[v0 + tid];
        __syncthreads();
        int cmax = cntS[127];   // depth sorted -> cnt nondecreasing; tile active: ub0 < cmax
        int creg[8];
#pragma unroll
        for (int i = 0; i < 8; i++) creg[i] = cntS[((i >> 2) << 6) + 4 * ty + (i & 3)];
        float t1v[8], t2v[8]; int t1i[8], t2i[8];
#pragma unroll
        for (int i = 0; i < 8; i++) { t1v[i] = NEGV; t2v[i] = NEGV; t1i[i] = 0x7fffffff; t2i[i] = 0x7fffffff; }
        int uend = ub0 + SEG; if (uend > cmax) uend = cmax;
        for (int ub = ub0; ub < uend; ub += UT) {
            float acc[8][8] = {};
            for (int k0 = 0; k0 < 128; k0 += 32) {
                __syncthreads();
                // coalesced staging: lanes 0..7 cover k within a row (128B contig),
                // rows advance every 8 lanes. Transposed ds_writes: 4-way conflict (pad 132).
#pragma unroll
                for (int p = 0; p < 4; p++) {
                    int q = p * 256 + tid;          // 0..1023
                    int r = q >> 3;                 // 0..127 tile row
                    int kq = q & 7;                 // float4 group within 32-k chunk
                    float4 va = *(const float4*)&Ht[(size_t)(v0 + r) * HH + k0 + 4 * kq];
                    HtS[(4 * kq + 0) * 132 + r] = va.x;
                    HtS[(4 * kq + 1) * 132 + r] = va.y;
                    HtS[(4 * kq + 2) * 132 + r] = va.z;
                    HtS[(4 * kq + 3) * 132 + r] = va.w;
                    float4 vb = *(const float4*)&Hs[(size_t)(ub + r) * HH + k0 + 4 * kq];
                    HsS[(4 * kq + 0) * 132 + r] = vb.x;
                    HsS[(4 * kq + 1) * 132 + r] = vb.y;
                    HsS[(4 * kq + 2) * 132 + r] = vb.z;
                    HsS[(4 * kq + 3) * 132 + r] = vb.w;
                }
                __syncthreads();
#pragma unroll 4
                for (int kk = 0; kk < 32; kk++) {
                    float4 a0 = *(const float4*)&HtS[kk * 132 + 4 * ty];
                    float4 a1 = *(const float4*)&HtS[kk * 132 + 64 + 4 * ty];
                    float4 b0 = *(const float4*)&HsS[kk * 132 + 4 * tx];
                    float4 b1 = *(const float4*)&HsS[kk * 132 + 64 + 4 * tx];
                    float av[8] = {a0.x, a0.y, a0.z, a0.w, a1.x, a1.y, a1.z, a1.w};
                    float bv[8] = {b0.x, b0.y, b0.z, b0.w, b1.x, b1.y, b1.z, b1.w};
#pragma unroll
                    for (int i = 0; i < 8; i++)
#pragma unroll
                        for (int j = 0; j < 8; j++)
                            acc[i][j] = fmaf(av[i], bv[j], acc[i][j]);
                }
            }
            // fold this u-tile into per-thread running top-2
#pragma unroll
            for (int i = 0; i < 8; i++) {
                int c = creg[i];
#pragma unroll
                for (int j = 0; j < 8; j++) {
                    int u = ub + ((j >> 2) << 6) + 4 * tx + (j & 3);
                    float val = (u < c) ? acc[i][j] : NEGV;   // masked: NEG with real index
                    if (val > t1v[i] || (val == t1v[i] && u < t1i[i])) {
                        t2v[i] = t1v[i]; t2i[i] = t1i[i]; t1v[i] = val; t1i[i] = u;
                    } else if (val > t2v[i] || (val == t2v[i] && u < t2i[i])) {
                        t2v[i] = val; t2i[i] = u;
                    }
                }
            }
        }
        __syncthreads();
        // cross-thread merge: reuse tiles as (val,idx) buffers, q-major (2-way banks on read)
        float* mv = HsS;
        int* mi = (int*)HtS;
#pragma unroll
        for (int i = 0; i < 8; i++) {
            int row = ((i >> 2) << 6) + 4 * ty + (i & 3);
            mv[(tx * 2 + 0) * 128 + row] = t1v[i]; mi[(tx * 2 + 0) * 128 + row] = t1i[i];
            mv[(tx * 2 + 1) * 128 + row] = t2v[i]; mi[(tx * 2 + 1) * 128 + row] = t2i[i];
        }
        __syncthreads();
        if (tid < 128) {
            float v1 = NEGV, v2 = NEGV; int i1 = 0x7fffffff, i2 = 0x7fffffff;
            for (int q = 0; q < 32; q++) {
                float val = mv[q * 128 + tid]; int idx = mi[q * 128 + tid];
                if (val > v1 || (val == v1 && idx < i1)) { v2 = v1; i2 = i1; v1 = val; i1 = idx; }
                else if (val > v2 || (val == v2 && idx < i2)) { v2 = val; i2 = idx; }
            }
            int o = ((v0 + tid) * NSEG + seg) * 2;
            pval[o] = v1;     pidx[o] = i1;
            pval[o + 1] = v2; pidx[o + 1] = i2;
        }
        // loop back: tsh handshake syncs separate this tile's LDS reads from next staging
    }
}

// ---------------- stage 2: merge segment partials, emit top_vals/top_idx ----------------

__global__ __launch_bounds__(256) void k_top2_merge(const float* __restrict__ pval, const int* __restrict__ pidx,
                                                    const int* __restrict__ nact,
                                                    float* __restrict__ out, int* __restrict__ tidx) {
    int v = blockIdx.x * 256 + threadIdx.x;
    if (v >= NN) return;
    int na = nact[v >> 7];
    float v1 = NEGV, v2 = NEGV; int i1 = 0x7fffffff, i2 = 0x7fffffff;
    if (na == 0) { i1 = 0; i2 = 1; }
    for (int t = 0; t < na * 2; t++) {
        float val = pval[v * (NSEG * 2) + t]; int idx = pidx[v * (NSEG * 2) + t];
        if (val > v1 || (val == v1 && idx < i1)) { v2 = v1; i2 = i1; v1 = val; i1 = idx; }
        else if (val > v2 || (val == v2 && idx < i2)) { v2 = val; i2 = idx; }
    }
    out[v * 2 + 0] = v1; out[v * 2 + 1] = v2;                    // top_vals
    out[2 * NN * 2 + v * 2 + 0] = (float)i1;                     // top_idx
    out[2 * NN * 2 + v * 2 + 1] = (float)i2;
    tidx[v * 2] = i1; tidx[v * 2 + 1] = i2;
}

// ---------------- inversion-bit epilogue: logit = inv2 . relu(P[u]+Q[v]+cz) + b ----------------

__global__ __launch_bounds__(256) void k_inv(const float* __restrict__ P, const float* __restrict__ Q,
                                             const float* __restrict__ cz, const float* __restrict__ w2,
                                             const float* __restrict__ b2, const int* __restrict__ tidx,
                                             float* __restrict__ out) {
    int gid = blockIdx.x * 256 + threadIdx.x;
    int wid = gid >> 6;
    int lane = gid & 63;
    if (wid >= NN * 2) return;
    int v = wid >> 1;
    int u = tidx[wid]; if (u > NN - 1) u = NN - 1; if (u < 0) u = 0;
    float h0 = fmaxf(P[u * HH + lane] + Q[v * HH + lane] + cz[lane], 0.f);
    float h1 = fmaxf(P[u * HH + 64 + lane] + Q[v * HH + 64 + lane] + cz[64 + lane], 0.f);
    float p = h0 * w2[lane] + h1 * w2[64 + lane];
    for (int off = 32; off >= 1; off >>= 1) p += __shfl_down(p, off, 64);
    if (lane == 0) {
        float logit = p + b2[0];
        out[NN * 2 + wid] = logit;                               // inv_logit
        out[3 * NN * 2 + wid] = (logit > 0.f) ? 1.f : 0.f;       // inv_bit
    }
}

// ---------------- launch ----------------

extern "C" void kernel_launch(void* const* d_in, const int* in_sizes, int n_in,
                              void* d_out, int out_size, void* d_ws, size_t ws_size,
                              hipStream_t stream) {
    const float* x       = (const float*)d_in[0];
    const float* z       = (const float*)d_in[1];
    const int*   eidx    = (const int*)d_in[2];
    const int*   depth   = (const int*)d_in[3];
    const float* conv1_w = (const float*)d_in[4];
    const float* conv1_b = (const float*)d_in[5];
    const float* conv2_w = (const float*)d_in[6];
    const float* conv2_b = (const float*)d_in[7];
    const float* np1_w   = (const float*)d_in[8];
    const float* np1_b   = (const float*)d_in[9];
    const float* np2_w   = (const float*)d_in[10];
    const float* np2_b   = (const float*)d_in[11];
    const float* src_w   = (const float*)d_in[12];
    const float* tgt_w   = (const float*)d_in[13];
    const float* inv1_w  = (const float*)d_in[14];
    const float* inv1_b  = (const float*)d_in[15];
    const float* inv2_w  = (const float*)d_in[16];
    const float* inv2_b  = (const float*)d_in[17];
    float* out = (float*)d_out;
    float* wsf = (float*)d_ws;

    const int NH = NN * HH;
    float* b0 = wsf;                     // xw1/xw2, later Ht
    float* b1 = wsf + (size_t)NH;        // later Hs
    float* b2 = wsf + 2 * (size_t)NH;    // h1/h2, later P
    float* b3 = wsf + 3 * (size_t)NH;    // t, later Q
    float* b4 = wsf + 4 * (size_t)NH;    // h3; dead after projections -> partial bufs
    float* T  = wsf + 5 * (size_t)NH;    // 7 x 16384 transposed weights
    float* c1 = T + 7 * 16384;
    float* cz = c1 + 128;
    float* rsq  = cz + 128;
    float* dinv = rsq + NN;
    int* degi   = (int*)(dinv + NN);
    int* rowptr = degi + NN;             // NN+1
    int* cursor = rowptr + NN + 1;
    int* cnt    = cursor + NN;
    int* nact   = cnt + NN;              // 64
    int* ntiles = nact + 64;
    int* tctr   = ntiles + 1;
    int* tidx   = tctr + 1;              // 2*NN
    int* tlist  = tidx + 2 * NN;         // <= 2048
    int* ecsr   = tlist + 2048;          // EE
    // partial top-2 buffers live in b4's space (h3 dead by stage1 time): exactly NH
    float* pval = b4;                    // NN*NSEG*2 = 524288 floats
    int*   pidx = (int*)(b4 + NN * NSEG * 2);

    const int* esrc = eidx;
    const int* edst = eidx + EE;

    hipMemsetAsync(degi, 0, NN * sizeof(int), stream);
    hipMemsetAsync(cursor, 0, NN * sizeof(int), stream);
    hipMemsetAsync(tctr, 0, sizeof(int), stream);
    k_prep<<<dim3(64, 8), 256, 0, stream>>>(conv2_w, np1_w, np2_w, src_w, tgt_w, inv1_w,
                                            np1_b, inv1_b, z, T, c1, cz);
    k_deg<<<EE / 256, 256, 0, stream>>>(edst, degi);
    k_rsq<<<NN / 256, 256, 0, stream>>>(degi, dinv, rsq);
    k_scan<<<1, 1024, 0, stream>>>(degi, rowptr);
    k_fill<<<EE / 256, 256, 0, stream>>>(esrc, edst, rowptr, cursor, ecsr);
    k_xw1<<<NH / 256, 256, 0, stream>>>(x, conv1_w, b0);
    k_gather<<<NN * 64 / 256, 256, 0, stream>>>(rowptr, ecsr, rsq, dinv, b0, conv1_b, b2);   // h1
    k_gemm128<<<256, 256, 0, stream>>>(b2, T + 0 * 16384, nullptr, b0, 0);                   // xw2
    k_gather<<<NN * 64 / 256, 256, 0, stream>>>(rowptr, ecsr, rsq, dinv, b0, conv2_b, b2);   // h2
    k_gemm128<<<256, 256, 0, stream>>>(b2, T + 1 * 16384, c1, b3, 1);      // t = relu(h2@np1h^T + c1)
    k_gemm128<<<256, 256, 0, stream>>>(b3, T + 2 * 16384, np2_b, b4, 0);   // h3
    k_gemm128x4<<<dim3(256, 4), 256, 0, stream>>>(b4, T, b0, b1, b2, b3);  // Ht, Hs, P, Q
    k_cnt_valid<<<NN / 256, 256, 0, stream>>>(depth, x, cnt, out);
    k_tiles<<<1, 64, 0, stream>>>(cnt, nact, tlist, ntiles);
    k_top2_stage1<<<768, 256, 0, stream>>>(b0, b1, cnt, tlist, ntiles, tctr, pval, pidx);
    k_top2_merge<<<NN / 256, 256, 0, stream>>>(pval, pidx, nact, out, tidx);
    k_inv<<<(NN * 2 * 64) / 256, 256, 0, stream>>>(b2, b3, cz, inv2_w, inv2_b, tidx, out);
}